// Round 1
// baseline (230.364 us; speedup 1.0000x reference)
//
#include <hip/hip_runtime.h>

// Problem constants (fixed by the reference)
#define BB 4
#define T 128           // T1 == T2
#define D 300
#define D4 75           // D/4 float4 chunks
#define NROW 512        // BB*T

// ---------------- Kernel A: projections q = x@WQ.T+bQ, k/v = x@WK.T+bK ----
// grid: 3 sources * 64 row-blocks = 192 blocks, 320 threads.
// Each block computes 8 rows x 300 outputs of one projection.
__global__ __launch_bounds__(320) void proj_kernel(
    const float* __restrict__ query, const float* __restrict__ key,
    const float* __restrict__ value,
    const float* __restrict__ WQ, const float* __restrict__ bQ,
    const float* __restrict__ WK, const float* __restrict__ bK,
    float* __restrict__ qkv /* [3][512][300] */)
{
    const int src  = blockIdx.x >> 6;    // 0=q,1=k,2=v
    const int rblk = blockIdx.x & 63;
    const int r0   = rblk * 8;
    const float* in   = (src == 0) ? query : (src == 1 ? key : value);
    const float* W    = (src == 0) ? WQ : WK;
    const float* bias = (src == 0) ? bQ : bK;
    float* out = qkv + src * (NROW * D);

    __shared__ __align__(16) float lds_in[8 * D];   // 9.6 KB
    for (int idx = threadIdx.x; idx < 8 * D; idx += 320)
        lds_in[idx] = in[r0 * D + idx];
    __syncthreads();

    const int t = threadIdx.x;
    if (t < D) {
        float acc[8];
        const float bv = bias[t];
        #pragma unroll
        for (int r = 0; r < 8; ++r) acc[r] = bv;
        const float4* W4 = (const float4*)(W + t * D);   // 1200B rows: 16B aligned
        for (int e4 = 0; e4 < D4; ++e4) {
            const float4 w = W4[e4];
            #pragma unroll
            for (int r = 0; r < 8; ++r) {
                const float4 x = *(const float4*)(&lds_in[r * D + e4 * 4]);
                acc[r] += w.x * x.x + w.y * x.y + w.z * x.z + w.w * x.w;
            }
        }
        #pragma unroll
        for (int r = 0; r < 8; ++r)
            out[(r0 + r) * D + t] = acc[r];
    }
}

// ---------------- Kernel B: scores -> double softmax -> weighted sum ------
// grid: 512 blocks (one per (b,i)), 320 threads (5 waves).
__global__ __launch_bounds__(320) void attn_kernel(
    const float* __restrict__ hL, const float* __restrict__ hR,
    const float* __restrict__ qkv, float* __restrict__ outp)
{
    const int b = blockIdx.x >> 7;
    const int i = blockIdx.x & 127;

    const float* qp    = qkv + (b * T + i) * D;
    const float* kbase = qkv + NROW * D + b * T * D;
    const float* vbase = qkv + 2 * NROW * D + b * T * D;

    __shared__ __align__(16) float q_lds[D];
    __shared__ float sc[T];
    __shared__ __align__(16) float red[4][D4 * 4];

    for (int idx = threadIdx.x; idx < D; idx += 320) q_lds[idx] = qp[idx];
    __syncthreads();

    const int wave = threadIdx.x >> 6;
    const int lane = threadIdx.x & 63;

    // ---- pass 1: scores[j] = sum_d (q_d + hL[i,j,d]) * (k_jd + hR[j,i,d]) ----
    const float4* hL4 = (const float4*)(hL + (size_t)(b * T + i) * T * D);
    for (int j = wave; j < T; j += 5) {
        const float4* hRrow = (const float4*)(hR + ((size_t)(b * T + j) * T + i) * D);
        const float4* krow  = (const float4*)(kbase + j * D);
        float4 a = {0.f, 0.f, 0.f, 0.f};
        #pragma unroll
        for (int it = 0; it < 2; ++it) {
            const int d4 = lane + it * 64;
            if (d4 < D4) {
                const float4 l  = hL4[j * D4 + d4];
                const float4 r  = hRrow[d4];
                const float4 kk = krow[d4];
                const float4 qq = *(const float4*)(&q_lds[d4 * 4]);
                a.x += (qq.x + l.x) * (kk.x + r.x);
                a.y += (qq.y + l.y) * (kk.y + r.y);
                a.z += (qq.z + l.z) * (kk.z + r.z);
                a.w += (qq.w + l.w) * (kk.w + r.w);
            }
        }
        float s = a.x + a.y + a.z + a.w;
        #pragma unroll
        for (int off = 32; off > 0; off >>= 1)
            s += __shfl_down(s, off, 64);
        if (lane == 0) sc[j] = s;
    }
    __syncthreads();

    // ---- softmax + sharpening (wave 0 only; 2 scores per lane) ----
    if (wave == 0) {
        float s0 = sc[lane], s1 = sc[lane + 64];
        float m = fmaxf(s0, s1);
        #pragma unroll
        for (int off = 32; off > 0; off >>= 1) m = fmaxf(m, __shfl_xor(m, off, 64));
        float e0 = __expf(s0 - m), e1 = __expf(s1 - m);
        float sum = e0 + e1;
        #pragma unroll
        for (int off = 32; off > 0; off >>= 1) sum += __shfl_xor(sum, off, 64);
        const float inv = 1.0f / sum;
        // sharpen: softmax(1000 * p), clamp to [0,1]
        float t0 = 1000.0f * (e0 * inv), t1 = 1000.0f * (e1 * inv);
        float m2 = fmaxf(t0, t1);
        #pragma unroll
        for (int off = 32; off > 0; off >>= 1) m2 = fmaxf(m2, __shfl_xor(m2, off, 64));
        float f0 = __expf(t0 - m2), f1 = __expf(t1 - m2);
        float sum2 = f0 + f1;
        #pragma unroll
        for (int off = 32; off > 0; off >>= 1) sum2 += __shfl_xor(sum2, off, 64);
        const float inv2 = 1.0f / sum2;
        sc[lane]      = fminf(fmaxf(f0 * inv2, 0.f), 1.f);
        sc[lane + 64] = fminf(fmaxf(f1 * inv2, 0.f), 1.f);
    }
    __syncthreads();

    // ---- pass 2: out[d] = sum_j attn_j * (v[j,d] + hR[j,i,d]) ----
    const int tid = threadIdx.x;
    if (tid < 4 * D4) {
        const int grp = tid / D4;    // 0..3: j-split
        const int d4  = tid % D4;
        float4 acc = {0.f, 0.f, 0.f, 0.f};
        for (int j = grp; j < T; j += 4) {
            const float aj = sc[j];
            if (aj >= 1e-12f) {      // sharpened attn is ~one-hot; skip is exact to <1e-9
                const float4 v4 = *(const float4*)(vbase + j * D + d4 * 4);
                const float4 r4 = *(const float4*)(hR + ((size_t)(b * T + j) * T + i) * D + d4 * 4);
                acc.x += aj * (v4.x + r4.x);
                acc.y += aj * (v4.y + r4.y);
                acc.z += aj * (v4.z + r4.z);
                acc.w += aj * (v4.w + r4.w);
            }
        }
        *(float4*)(&red[grp][d4 * 4]) = acc;
    }
    __syncthreads();
    if (tid < D4) {
        float4 o = {0.f, 0.f, 0.f, 0.f};
        #pragma unroll
        for (int g = 0; g < 4; ++g) {
            const float4 p = *(const float4*)(&red[g][tid * 4]);
            o.x += p.x; o.y += p.y; o.z += p.z; o.w += p.w;
        }
        *(float4*)(outp + (size_t)(b * T + i) * D + tid * 4) = o;
    }
}

extern "C" void kernel_launch(void* const* d_in, const int* in_sizes, int n_in,
                              void* d_out, int out_size, void* d_ws, size_t ws_size,
                              hipStream_t stream) {
    const float* query = (const float*)d_in[0];
    const float* key   = (const float*)d_in[1];
    const float* value = (const float*)d_in[2];
    const float* hL    = (const float*)d_in[3];
    const float* hR    = (const float*)d_in[4];
    const float* WQ    = (const float*)d_in[5];
    const float* bQ    = (const float*)d_in[6];
    const float* WK    = (const float*)d_in[7];
    const float* bK    = (const float*)d_in[8];
    float* out = (float*)d_out;
    float* qkv = (float*)d_ws;   // needs 3*512*300*4 = 1.84 MB

    proj_kernel<<<dim3(192), dim3(320), 0, stream>>>(query, key, value, WQ, bQ, WK, bK, qkv);
    attn_kernel<<<dim3(512), dim3(320), 0, stream>>>(hL, hR, qkv, out);
}

// Round 2
// 227.436 us; speedup vs baseline: 1.0129x; 1.0129x over previous
//
#include <hip/hip_runtime.h>

// Problem constants (fixed by the reference)
#define BB 4
#define T 128           // T1 == T2
#define D 300
#define D4 75           // D/4 float4 chunks
#define NROW 512        // BB*T

// ---------------- Kernel A: projections q = x@WQ.T+bQ, k/v = x@WK.T+bK ----
// grid: 3 sources * 64 row-blocks = 192 blocks, 320 threads.
// Each block computes 8 rows x 300 outputs of one projection.
__global__ __launch_bounds__(320) void proj_kernel(
    const float* __restrict__ query, const float* __restrict__ key,
    const float* __restrict__ value,
    const float* __restrict__ WQ, const float* __restrict__ bQ,
    const float* __restrict__ WK, const float* __restrict__ bK,
    float* __restrict__ qkv /* [3][512][300] */)
{
    const int src  = blockIdx.x >> 6;    // 0=q,1=k,2=v
    const int rblk = blockIdx.x & 63;
    const int r0   = rblk * 8;
    const float* in   = (src == 0) ? query : (src == 1 ? key : value);
    const float* W    = (src == 0) ? WQ : WK;
    const float* bias = (src == 0) ? bQ : bK;
    float* out = qkv + src * (NROW * D);

    __shared__ __align__(16) float lds_in[8 * D];   // 9.6 KB
    for (int idx = threadIdx.x; idx < 8 * D; idx += 320)
        lds_in[idx] = in[r0 * D + idx];
    __syncthreads();

    const int t = threadIdx.x;
    if (t < D) {
        float acc[8];
        const float bv = bias[t];
        #pragma unroll
        for (int r = 0; r < 8; ++r) acc[r] = bv;
        const float4* W4 = (const float4*)(W + t * D);   // 1200B rows: 16B aligned
        for (int e4 = 0; e4 < D4; ++e4) {
            const float4 w = W4[e4];
            #pragma unroll
            for (int r = 0; r < 8; ++r) {
                const float4 x = *(const float4*)(&lds_in[r * D + e4 * 4]);
                acc[r] += w.x * x.x + w.y * x.y + w.z * x.z + w.w * x.w;
            }
        }
        #pragma unroll
        for (int r = 0; r < 8; ++r)
            out[(r0 + r) * D + t] = acc[r];
    }
}

// ---------------- Kernel B: scores -> double softmax -> weighted sum ------
// grid: 512 blocks (one per (b,i)), 1024 threads (16 waves).
// R1: 320 -> 1024 threads: 512*16 waves = 8192 = 100% of device wave slots.
// Previous 320-thread version was grid-capped at 26% occupancy (latency-bound:
// ran 70us even fully L3-resident).
__global__ __launch_bounds__(1024) void attn_kernel(
    const float* __restrict__ hL, const float* __restrict__ hR,
    const float* __restrict__ qkv, float* __restrict__ outp)
{
    const int b = blockIdx.x >> 7;
    const int i = blockIdx.x & 127;

    const float* qp    = qkv + (b * T + i) * D;
    const float* kbase = qkv + NROW * D + b * T * D;
    const float* vbase = qkv + 2 * NROW * D + b * T * D;

    __shared__ __align__(16) float q_lds[D];
    __shared__ float sc[T];
    __shared__ __align__(16) float red[12][D];   // 14.4 KB

    for (int idx = threadIdx.x; idx < D; idx += 1024) q_lds[idx] = qp[idx];
    __syncthreads();

    const int wave = threadIdx.x >> 6;   // 0..15
    const int lane = threadIdx.x & 63;

    // ---- pass 1: scores[j] = sum_d (q_d + hL[i,j,d]) * (k_jd + hR[j,i,d]) ----
    const float4* hL4 = (const float4*)(hL + (size_t)(b * T + i) * T * D);
    for (int j = wave; j < T; j += 16) {       // 8 iterations per wave
        const float4* hRrow = (const float4*)(hR + ((size_t)(b * T + j) * T + i) * D);
        const float4* krow  = (const float4*)(kbase + j * D);
        float4 a = {0.f, 0.f, 0.f, 0.f};
        #pragma unroll
        for (int it = 0; it < 2; ++it) {
            const int d4 = lane + it * 64;
            if (d4 < D4) {
                const float4 l  = hL4[j * D4 + d4];
                const float4 r  = hRrow[d4];
                const float4 kk = krow[d4];
                const float4 qq = *(const float4*)(&q_lds[d4 * 4]);
                a.x += (qq.x + l.x) * (kk.x + r.x);
                a.y += (qq.y + l.y) * (kk.y + r.y);
                a.z += (qq.z + l.z) * (kk.z + r.z);
                a.w += (qq.w + l.w) * (kk.w + r.w);
            }
        }
        float s = a.x + a.y + a.z + a.w;
        #pragma unroll
        for (int off = 32; off > 0; off >>= 1)
            s += __shfl_down(s, off, 64);
        if (lane == 0) sc[j] = s;
    }
    __syncthreads();

    // ---- softmax + sharpening (wave 0 only; 2 scores per lane) ----
    if (wave == 0) {
        float s0 = sc[lane], s1 = sc[lane + 64];
        float m = fmaxf(s0, s1);
        #pragma unroll
        for (int off = 32; off > 0; off >>= 1) m = fmaxf(m, __shfl_xor(m, off, 64));
        float e0 = __expf(s0 - m), e1 = __expf(s1 - m);
        float sum = e0 + e1;
        #pragma unroll
        for (int off = 32; off > 0; off >>= 1) sum += __shfl_xor(sum, off, 64);
        const float inv = 1.0f / sum;
        // sharpen: softmax(1000 * p), clamp to [0,1]
        float t0 = 1000.0f * (e0 * inv), t1 = 1000.0f * (e1 * inv);
        float m2 = fmaxf(t0, t1);
        #pragma unroll
        for (int off = 32; off > 0; off >>= 1) m2 = fmaxf(m2, __shfl_xor(m2, off, 64));
        float f0 = __expf(t0 - m2), f1 = __expf(t1 - m2);
        float sum2 = f0 + f1;
        #pragma unroll
        for (int off = 32; off > 0; off >>= 1) sum2 += __shfl_xor(sum2, off, 64);
        const float inv2 = 1.0f / sum2;
        sc[lane]      = fminf(fmaxf(f0 * inv2, 0.f), 1.f);
        sc[lane + 64] = fminf(fmaxf(f1 * inv2, 0.f), 1.f);
    }
    __syncthreads();

    // ---- pass 2: out[d] = sum_j attn_j * (v[j,d] + hR[j,i,d]) ----
    const int tid = threadIdx.x;
    if (tid < 12 * D4) {
        const int grp = tid / D4;    // 0..11: j-split
        const int d4  = tid % D4;
        float4 acc = {0.f, 0.f, 0.f, 0.f};
        for (int j = grp; j < T; j += 12) {
            const float aj = sc[j];
            if (aj >= 1e-12f) {      // sharpened attn is ~one-hot; skip is exact to <1e-9
                const float4 v4 = *(const float4*)(vbase + j * D + d4 * 4);
                const float4 r4 = *(const float4*)(hR + ((size_t)(b * T + j) * T + i) * D + d4 * 4);
                acc.x += aj * (v4.x + r4.x);
                acc.y += aj * (v4.y + r4.y);
                acc.z += aj * (v4.z + r4.z);
                acc.w += aj * (v4.w + r4.w);
            }
        }
        *(float4*)(&red[grp][d4 * 4]) = acc;
    }
    __syncthreads();
    if (tid < D4) {
        float4 o = {0.f, 0.f, 0.f, 0.f};
        #pragma unroll
        for (int g = 0; g < 12; ++g) {
            const float4 p = *(const float4*)(&red[g][tid * 4]);
            o.x += p.x; o.y += p.y; o.z += p.z; o.w += p.w;
        }
        *(float4*)(outp + (size_t)(b * T + i) * D + tid * 4) = o;
    }
}

extern "C" void kernel_launch(void* const* d_in, const int* in_sizes, int n_in,
                              void* d_out, int out_size, void* d_ws, size_t ws_size,
                              hipStream_t stream) {
    const float* query = (const float*)d_in[0];
    const float* key   = (const float*)d_in[1];
    const float* value = (const float*)d_in[2];
    const float* hL    = (const float*)d_in[3];
    const float* hR    = (const float*)d_in[4];
    const float* WQ    = (const float*)d_in[5];
    const float* bQ    = (const float*)d_in[6];
    const float* WK    = (const float*)d_in[7];
    const float* bK    = (const float*)d_in[8];
    float* out = (float*)d_out;
    float* qkv = (float*)d_ws;   // needs 3*512*300*4 = 1.84 MB

    proj_kernel<<<dim3(192), dim3(320), 0, stream>>>(query, key, value, WQ, bQ, WK, bK, qkv);
    attn_kernel<<<dim3(512), dim3(1024), 0, stream>>>(hL, hR, qkv, out);
}